// Round 1
// baseline (3158.768 us; speedup 1.0000x reference)
//
#include <hip/hip_runtime.h>

// LightGCN encoder: ego = concat(user_emb, item_emb) [150000 x 64]
// h_{k+1} = A h_k (COO SpMM, 4.8M nnz), out = (ego + h1 + h2 + h3)/4.
//
// Layout decisions:
//  - EMB == 64 == wavefront size: one wave per edge, lane d handles dim d.
//    Gather x[col*64+d] and atomicAdd y[row*64+d] are each one coalesced
//    256B transaction per wave; row/col/val loads are wave-uniform broadcasts.
//  - h double-buffer in d_ws (2 x 38.4 MB); accumulator kept in d_out,
//    pre-scaled by 0.25 so no final normalization pass is needed.

#define USER_NUM 100000
#define ITEM_NUM 50000
#define N_NODES (USER_NUM + ITEM_NUM)
#define EMB 64
#define NFLOAT (N_NODES * EMB)        // 9,600,000 floats
#define USER_FLOATS (USER_NUM * EMB)  // 6,400,000 floats

// Build h0 = ego and acc = 0.25*ego (acc lives in d_out).
__global__ __launch_bounds__(256) void lgcn_init(const float* __restrict__ user,
                                                 const float* __restrict__ item,
                                                 float* __restrict__ h,
                                                 float* __restrict__ acc) {
    const int total4 = NFLOAT / 4;
    const int user4 = USER_FLOATS / 4;
    int stride = gridDim.x * blockDim.x;
    for (int i = blockIdx.x * blockDim.x + threadIdx.x; i < total4; i += stride) {
        float4 v;
        if (i < user4) {
            v = reinterpret_cast<const float4*>(user)[i];
        } else {
            v = reinterpret_cast<const float4*>(item)[i - user4];
        }
        reinterpret_cast<float4*>(h)[i] = v;
        float4 s = make_float4(v.x * 0.25f, v.y * 0.25f, v.z * 0.25f, v.w * 0.25f);
        reinterpret_cast<float4*>(acc)[i] = s;
    }
}

// One wave per edge: y[row] += val * x[col], lane d owns dim d.
__global__ __launch_bounds__(256) void lgcn_spmm(const int* __restrict__ row,
                                                 const int* __restrict__ col,
                                                 const float* __restrict__ vals,
                                                 const float* __restrict__ x,
                                                 float* __restrict__ y,
                                                 int nnz) {
    const int lane = threadIdx.x & 63;
    const int wave_in_block = threadIdx.x >> 6;
    const int waves_per_block = blockDim.x >> 6;
    long long e = (long long)blockIdx.x * waves_per_block + wave_in_block;
    const long long estride = (long long)gridDim.x * waves_per_block;
    for (; e < nnz; e += estride) {
        int r = row[e];
        int c = col[e];
        float v = vals[e];
        float xv = x[(long long)c * EMB + lane];
        atomicAdd(&y[(long long)r * EMB + lane], v * xv);
    }
}

// acc += 0.25 * h   (vectorized)
__global__ __launch_bounds__(256) void lgcn_acc(const float* __restrict__ h,
                                                float* __restrict__ acc) {
    const int total4 = NFLOAT / 4;
    int stride = gridDim.x * blockDim.x;
    for (int i = blockIdx.x * blockDim.x + threadIdx.x; i < total4; i += stride) {
        float4 hv = reinterpret_cast<const float4*>(h)[i];
        float4 av = reinterpret_cast<float4*>(acc)[i];
        av.x += 0.25f * hv.x;
        av.y += 0.25f * hv.y;
        av.z += 0.25f * hv.z;
        av.w += 0.25f * hv.w;
        reinterpret_cast<float4*>(acc)[i] = av;
    }
}

extern "C" void kernel_launch(void* const* d_in, const int* in_sizes, int n_in,
                              void* d_out, int out_size, void* d_ws, size_t ws_size,
                              hipStream_t stream) {
    const float* user_emb = (const float*)d_in[0];
    const float* item_emb = (const float*)d_in[1];
    const int* adj_row = (const int*)d_in[2];
    const int* adj_col = (const int*)d_in[3];
    const float* adj_vals = (const float*)d_in[4];
    const int nnz = in_sizes[2];

    float* acc = (float*)d_out;               // [N_NODES * EMB]
    float* h0 = (float*)d_ws;                 // 38.4 MB
    float* h1 = h0 + NFLOAT;                  // 38.4 MB

    const size_t HBYTES = (size_t)NFLOAT * sizeof(float);

    // init: h0 = ego, acc = 0.25*ego
    lgcn_init<<<2048, 256, 0, stream>>>(user_emb, item_emb, h0, acc);

    float* h_cur = h0;
    float* h_nxt = h1;
    for (int layer = 0; layer < 3; ++layer) {
        hipMemsetAsync(h_nxt, 0, HBYTES, stream);
        // 4 waves/block, 2048 blocks = 8192 waves (full CU occupancy), grid-stride
        lgcn_spmm<<<2048, 256, 0, stream>>>(adj_row, adj_col, adj_vals,
                                            h_cur, h_nxt, nnz);
        lgcn_acc<<<2048, 256, 0, stream>>>(h_nxt, acc);
        float* t = h_cur; h_cur = h_nxt; h_nxt = t;
    }
}